// Round 4
// baseline (22827.696 us; speedup 1.0000x reference)
//
#include <hip/hip_runtime.h>
#include <stdint.h>
#include <stddef.h>

typedef __bf16 bf16;
typedef __bf16 bf16x8 __attribute__((ext_vector_type(8)));
typedef __bf16 bf16x4 __attribute__((ext_vector_type(4)));
typedef float  f32x4  __attribute__((ext_vector_type(4)));

#define B_ 8
#define T_ 2048
#define D_ 1024
#define L_ 2

#define AS1C(p) ((const __attribute__((address_space(1))) void*)(p))
#define AS3(p)  ((__attribute__((address_space(3))) void*)(p))

// Compact frame layout (h-state after step t), 16384 B per frame:
//   byte(t, b, n) = t*16384 + (n>>5)*512 + (((n&31)>>3)*8 + b)*16 + (n&7)*2
// b in [0,8), n in [0,1024). Expanded to 32KB MFMA-A-fragment layout in LDS
// during staging (rows 8..15 of each 16-row fragment are finite dummies).

// ---------------- f32 -> bf16 convert (weights) ----------------
__global__ __launch_bounds__(256) void cvt_kernel(const float* __restrict__ in,
                                                  bf16* __restrict__ out, int n4) {
  int i = blockIdx.x * 256 + threadIdx.x;
  if (i >= n4) return;
  float4 v = ((const float4*)in)[i];
  bf16x4 o = { (bf16)v.x, (bf16)v.y, (bf16)v.z, (bf16)v.w };
  ((bf16x4*)out)[i] = o;
}

// ---------------- LayerNorm ----------------
__global__ __launch_bounds__(256) void ln_kernel(const float* __restrict__ x,
                                                 const float* __restrict__ g,
                                                 const float* __restrict__ b,
                                                 bf16* __restrict__ xn) {
  const int row = blockIdx.x;
  const int tid = threadIdx.x;
  const float4 v = ((const float4*)(x + (size_t)row * D_))[tid];
  float s1 = v.x + v.y + v.z + v.w;
  float s2 = v.x * v.x + v.y * v.y + v.z * v.z + v.w * v.w;
#pragma unroll
  for (int off = 1; off < 64; off <<= 1) {
    s1 += __shfl_xor(s1, off);
    s2 += __shfl_xor(s2, off);
  }
  __shared__ float r1[4], r2[4];
  if ((tid & 63) == 0) { r1[tid >> 6] = s1; r2[tid >> 6] = s2; }
  __syncthreads();
  s1 = r1[0] + r1[1] + r1[2] + r1[3];
  s2 = r2[0] + r2[1] + r2[2] + r2[3];
  const float mu = s1 * (1.f / D_);
  const float var = s2 * (1.f / D_) - mu * mu;
  const float rs = rsqrtf(var + 1e-5f);
  const float4 gv = ((const float4*)g)[tid];
  const float4 bv = ((const float4*)b)[tid];
  bf16x4 o = { (bf16)((v.x - mu) * rs * gv.x + bv.x),
               (bf16)((v.y - mu) * rs * gv.y + bv.y),
               (bf16)((v.z - mu) * rs * gv.z + bv.z),
               (bf16)((v.w - mu) * rs * gv.w + bv.w) };
  ((bf16x4*)(xn + (size_t)row * D_))[tid] = o;
}

// ---------------- bf16 MFMA GEMM, C[m,n] = sum_k A[m,k]*Bw[n,k] (+bias +resid) --
__global__ __launch_bounds__(256) void gemm_bt(const bf16* __restrict__ A,
                                               const bf16* __restrict__ Bw,
                                               const float* __restrict__ bias,
                                               const float* __restrict__ resid,
                                               float* __restrict__ C,
                                               int M, int N, int K) {
  __shared__ bf16 As[128 * 32];
  __shared__ bf16 Bs[128 * 32];
  const int tid = threadIdx.x;
  const int lane = tid & 63;
  const int wave = tid >> 6;
  const int m0 = blockIdx.y * 128;
  const int n0 = blockIdx.x * 128;
  const int wm = (wave >> 1) * 64;
  const int wn = (wave & 1) * 64;
  f32x4 acc[4][4] = {};

  for (int kt = 0; kt < K; kt += 32) {
#pragma unroll
    for (int it = 0; it < 2; ++it) {
      const int gidx = it * 256 + tid;
      const int row = gidx >> 2;
      const int col = (gidx & 3) << 3;
      __builtin_amdgcn_global_load_lds(AS1C(A + (size_t)(m0 + row) * K + kt + col),
                                       AS3(&As[gidx * 8]), 16, 0, 0);
      __builtin_amdgcn_global_load_lds(AS1C(Bw + (size_t)(n0 + row) * K + kt + col),
                                       AS3(&Bs[gidx * 8]), 16, 0, 0);
    }
    __syncthreads();
    bf16x8 af[4], bfr[4];
#pragma unroll
    for (int i = 0; i < 4; ++i)
      af[i] = *(const bf16x8*)&As[(wm + i * 16 + (lane & 15)) * 32 + (lane >> 4) * 8];
#pragma unroll
    for (int j = 0; j < 4; ++j)
      bfr[j] = *(const bf16x8*)&Bs[(wn + j * 16 + (lane & 15)) * 32 + (lane >> 4) * 8];
#pragma unroll
    for (int i = 0; i < 4; ++i)
#pragma unroll
      for (int j = 0; j < 4; ++j)
        acc[i][j] = __builtin_amdgcn_mfma_f32_16x16x32_bf16(af[i], bfr[j], acc[i][j], 0, 0, 0);
    __syncthreads();
  }

  const int cr = (lane >> 4) * 4;
  const int cc = lane & 15;
#pragma unroll
  for (int i = 0; i < 4; ++i) {
#pragma unroll
    for (int j = 0; j < 4; ++j) {
      const int mb = m0 + wm + i * 16 + cr;
      const int n = n0 + wn + j * 16 + cc;
      const float bn = bias ? bias[n] : 0.f;
#pragma unroll
      for (int r = 0; r < 4; ++r) {
        const size_t idx = (size_t)(mb + r) * N + n;
        float vv = acc[i][j][r] + bn;
        if (resid) vv += resid[idx];
        C[idx] = vv;
      }
    }
  }
}

// ---- same GEMM but A comes from the compact frame-layout h buffer ----
__global__ __launch_bounds__(256) void gemm_hfrag(const char* __restrict__ Hb,
                                                  const bf16* __restrict__ Bw,
                                                  const float* __restrict__ bias,
                                                  const float* __restrict__ resid,
                                                  float* __restrict__ C,
                                                  int M, int N, int K) {
  __shared__ bf16 As[128 * 32];
  __shared__ bf16 Bs[128 * 32];
  const int tid = threadIdx.x;
  const int lane = tid & 63;
  const int wave = tid >> 6;
  const int m0 = blockIdx.y * 128;
  const int n0 = blockIdx.x * 128;
  const int wm = (wave >> 1) * 64;
  const int wn = (wave & 1) * 64;
  f32x4 acc[4][4] = {};

  for (int kt = 0; kt < K; kt += 32) {
#pragma unroll
    for (int it = 0; it < 2; ++it) {
      const int g = it * 256 + tid;
      const int r = g >> 2;
      const int sub = g & 3;
      const int R = m0 + r;
      const int bb = R >> 11;
      const int tt = R & (T_ - 1);
      const char* src = Hb + (size_t)tt * 16384 + (size_t)(kt >> 5) * 512
                        + (sub * 8 + bb) * 16;
      __builtin_amdgcn_global_load_lds(AS1C(src), AS3(&As[g * 8]), 16, 0, 0);
      __builtin_amdgcn_global_load_lds(AS1C(Bw + (size_t)(n0 + r) * K + kt + (sub << 3)),
                                       AS3(&Bs[g * 8]), 16, 0, 0);
    }
    __syncthreads();
    bf16x8 af[4], bfr[4];
#pragma unroll
    for (int i = 0; i < 4; ++i)
      af[i] = *(const bf16x8*)&As[(wm + i * 16 + (lane & 15)) * 32 + (lane >> 4) * 8];
#pragma unroll
    for (int j = 0; j < 4; ++j)
      bfr[j] = *(const bf16x8*)&Bs[(wn + j * 16 + (lane & 15)) * 32 + (lane >> 4) * 8];
#pragma unroll
    for (int i = 0; i < 4; ++i)
#pragma unroll
      for (int j = 0; j < 4; ++j)
        acc[i][j] = __builtin_amdgcn_mfma_f32_16x16x32_bf16(af[i], bfr[j], acc[i][j], 0, 0, 0);
    __syncthreads();
  }

  const int cr = (lane >> 4) * 4;
  const int cc = lane & 15;
#pragma unroll
  for (int i = 0; i < 4; ++i) {
#pragma unroll
    for (int j = 0; j < 4; ++j) {
      const int mb = m0 + wm + i * 16 + cr;
      const int n = n0 + wn + j * 16 + cc;
      const float bn = bias[n];
#pragma unroll
      for (int r = 0; r < 4; ++r) {
        const size_t idx = (size_t)(mb + r) * N + n;
        C[idx] = acc[i][j][r] + bn + resid[idx];
      }
    }
  }
}

// ---------------- scan: 8 WGs x 512 thr, W_h in VGPRs, MFMA recurrence --------
// Sync: slot-per-wave release-stores + parallel 64-slot poll (no atomic RMW).
// Publish: LDS transpose -> 32 contiguous 8B agent stores per wave.
__global__ __launch_bounds__(512, 2) void scan_kernel(const float* __restrict__ uvb,
                                                      const bf16* __restrict__ Wh,
                                                      const float* __restrict__ bh,
                                                      char* __restrict__ Hb,
                                                      unsigned* __restrict__ slots) {
  const int tid = threadIdx.x;
  const int lane = tid & 63;
  const int wv = tid >> 6;
  const int Wg = blockIdx.x * 8 + wv;      // global wave id 0..63
  const int n0 = Wg * 16;                  // 16 output cols per wave
  const int kkw = Wg >> 1;                 // this wave's frame k-chunk
  const int c = lane & 15;                 // local col

  __shared__ __align__(16) char hA[2][32768];  // double-buffered A-frag frames
  __shared__ __align__(16) char tscr[8][256];  // per-wave publish transpose

  // W_h B-fragments: wB[kk] = W_h[n0+c][kk*32 + (lane>>4)*8 .. +8]
  bf16x8 wB[32];
#pragma unroll
  for (int kk = 0; kk < 32; ++kk)
    wB[kk] = *(const bf16x8*)(Wh + ((size_t)(n0 + c) << 10) + kk * 32 + ((lane >> 4) << 3));

  const float bh_n = bh[n0 + c];
  const int b0 = (lane >> 4) * 4;          // first batch (C-frag rows), lanes<32

  // staging granule precompute: LDS granule g = i*512 + tid
  int sgoff[4];
#pragma unroll
  for (int i = 0; i < 4; ++i) {
    const int g = i * 512 + tid;
    const int l16 = g & 63;
    sgoff[i] = (g >> 6) * 512 + ((l16 >> 4) * 8 + (l16 & 7)) * 16;  // row&7 dummies
  }

  // wave's 256B contiguous frame region
  const int wregion = kkw * 512 + (Wg & 1) * 256;

  float hs0 = 0.f, hs1 = 0.f, hs2 = 0.f, hs3 = 0.f;

  for (int t = 0; t < T_; ++t) {
    // ---- prefetch u,v for this step (hidden under the poll) ----
    float u0, u1, u2, u3, v0, v1, v2, v3;
    if (lane < 32) {
      const float* uvp = uvb + ((size_t)b0 * T_ + t) * 2048 + n0 + c;
      u0 = uvp[0];                          v0 = uvp[1024];
      u1 = uvp[(size_t)1 * T_ * 2048];      v1 = uvp[(size_t)1 * T_ * 2048 + 1024];
      u2 = uvp[(size_t)2 * T_ * 2048];      v2 = uvp[(size_t)2 * T_ * 2048 + 1024];
      u3 = uvp[(size_t)3 * T_ * 2048];      v3 = uvp[(size_t)3 * T_ * 2048 + 1024];
    }

    f32x4 asum = {0.f, 0.f, 0.f, 0.f};
    if (t > 0) {
      // ---- wait: every wave published frame[t-1] (parallel slot poll) ----
      const unsigned tgt = (unsigned)t;
      const unsigned* myslot = slots + lane * 16;
      unsigned sv = __hip_atomic_load(myslot, __ATOMIC_RELAXED, __HIP_MEMORY_SCOPE_AGENT);
      while (!__all((int)(sv >= tgt))) {
        __builtin_amdgcn_s_sleep(1);
        sv = __hip_atomic_load(myslot, __ATOMIC_RELAXED, __HIP_MEMORY_SCOPE_AGENT);
      }
      (void)__hip_atomic_load(slots, __ATOMIC_ACQUIRE, __HIP_MEMORY_SCOPE_AGENT);
      __builtin_amdgcn_sched_barrier(0);
      // ---- stage frame[t-1], expanding compact(16KB) -> fragment(32KB) ----
      const char* srcF = Hb + (size_t)(t - 1) * 16384;
      char* dstF = hA[t & 1];
#pragma unroll
      for (int i = 0; i < 4; ++i)
        __builtin_amdgcn_global_load_lds(AS1C(srcF + sgoff[i]),
                                         AS3(dstF + (i * 512 + tid) * 16), 16, 0, 0);
      __syncthreads();
      // ---- h @ W_h^T: 16 cols x 8 batches (frag rows 8..15 are dummies) ----
      f32x4 a0 = {0.f, 0.f, 0.f, 0.f}, a1 = {0.f, 0.f, 0.f, 0.f};
      f32x4 a2 = {0.f, 0.f, 0.f, 0.f}, a3 = {0.f, 0.f, 0.f, 0.f};
#pragma unroll
      for (int kk = 0; kk < 32; kk += 4) {
        bf16x8 f0 = *(const bf16x8*)(dstF + kk * 1024 + lane * 16);
        bf16x8 f1 = *(const bf16x8*)(dstF + (kk + 1) * 1024 + lane * 16);
        bf16x8 f2 = *(const bf16x8*)(dstF + (kk + 2) * 1024 + lane * 16);
        bf16x8 f3 = *(const bf16x8*)(dstF + (kk + 3) * 1024 + lane * 16);
        a0 = __builtin_amdgcn_mfma_f32_16x16x32_bf16(f0, wB[kk], a0, 0, 0, 0);
        a1 = __builtin_amdgcn_mfma_f32_16x16x32_bf16(f1, wB[kk + 1], a1, 0, 0, 0);
        a2 = __builtin_amdgcn_mfma_f32_16x16x32_bf16(f2, wB[kk + 2], a2, 0, 0, 0);
        a3 = __builtin_amdgcn_mfma_f32_16x16x32_bf16(f3, wB[kk + 3], a3, 0, 0, 0);
      }
      asum = (a0 + a1) + (a2 + a3);
      // no trailing barrier: hA is double-buffered; slot protocol prevents 2-ahead
    }

    // ---- epilogue: gate/cand, transpose via LDS, packed publish ----
    char* wscr = tscr[wv];
    if (lane < 32) {
#pragma unroll
      for (int r = 0; r < 4; ++r) {
        const float uu = (r == 0) ? u0 : (r == 1) ? u1 : (r == 2) ? u2 : u3;
        const float vv = (r == 0) ? v0 : (r == 1) ? v1 : (r == 2) ? v2 : v3;
        float& hh = (r == 0) ? hs0 : (r == 1) ? hs1 : (r == 2) ? hs2 : hs3;
        const float s = asum[r] + bh_n + vv;
        const float g = __builtin_amdgcn_rcpf(1.f + __expf(-uu));
        const float e = __expf(2.f * s);
        const float cand = 1.f - 2.f * __builtin_amdgcn_rcpf(e + 1.f);
        hh = fmaf(g, cand - hh, hh);
        // scratch layout == frame region layout: (c>>3)*128 + b*16 + (c&7)*2
        *(bf16*)(wscr + (c >> 3) * 128 + (b0 + r) * 16 + (c & 7) * 2) = (bf16)hh;
      }
    }
    asm volatile("s_waitcnt lgkmcnt(0)" ::: "memory");  // wave-local transpose done
    __builtin_amdgcn_sched_barrier(0);
    if (lane < 32) {
      const unsigned long long pv = *(const unsigned long long*)(wscr + lane * 8);
      char* dst = Hb + (size_t)t * 16384 + wregion + lane * 8;
      __hip_atomic_store((unsigned long long*)dst, pv,
                         __ATOMIC_RELAXED, __HIP_MEMORY_SCOPE_AGENT);
    }
    if (lane == 0)
      __hip_atomic_store(slots + Wg * 16, (unsigned)(t + 1),
                         __ATOMIC_RELEASE, __HIP_MEMORY_SCOPE_AGENT);
  }
}

extern "C" void kernel_launch(void* const* d_in, const int* in_sizes, int n_in,
                              void* d_out, int out_size, void* d_ws, size_t ws_size,
                              hipStream_t stream) {
  const float* x     = (const float*)d_in[0];
  const float* ln_g  = (const float*)d_in[1];
  const float* ln_b  = (const float*)d_in[2];
  const float* W_in  = (const float*)d_in[3];
  const float* b_in  = (const float*)d_in[4];
  const float* W_h   = (const float*)d_in[5];
  const float* b_h   = (const float*)d_in[6];
  const float* W_out = (const float*)d_in[7];
  const float* b_out = (const float*)d_in[8];
  float* out = (float*)d_out;

  char* ws = (char*)d_ws;
  size_t off = 0;
  auto alloc = [&](size_t bytes) -> void* {
    void* p = ws + off;
    off = (off + bytes + 255) & ~(size_t)255;
    return p;
  };
  bf16* wInB  = (bf16*)alloc((size_t)L_ * 2 * D_ * D_ * 2);
  bf16* wHB   = (bf16*)alloc((size_t)L_ * D_ * D_ * 2);
  bf16* wOutB = (bf16*)alloc((size_t)L_ * D_ * D_ * 2);
  bf16* Xn    = (bf16*)alloc((size_t)B_ * T_ * D_ * 2);
  float* uvb  = (float*)alloc((size_t)B_ * T_ * 2 * D_ * 4);
  char* Hb    = (char*)alloc((size_t)T_ * 16384);   // compact h frames (32 MB)
  unsigned* slots = (unsigned*)alloc(64 * 64);      // per-wave sync slots
  (void)ws_size; (void)in_sizes; (void)n_in; (void)out_size;

  {
    int n4 = L_ * 2 * D_ * D_ / 4;
    cvt_kernel<<<(n4 + 255) / 256, 256, 0, stream>>>(W_in, wInB, n4);
    n4 = L_ * D_ * D_ / 4;
    cvt_kernel<<<(n4 + 255) / 256, 256, 0, stream>>>(W_h, wHB, n4);
    cvt_kernel<<<(n4 + 255) / 256, 256, 0, stream>>>(W_out, wOutB, n4);
  }

  const int Mrows = B_ * T_;  // 16384
  for (int l = 0; l < L_; ++l) {
    const float* lin = (l == 0) ? x : out;
    ln_kernel<<<Mrows, 256, 0, stream>>>(lin, ln_g + l * D_, ln_b + l * D_, Xn);

    dim3 g1(2 * D_ / 128, Mrows / 128);
    gemm_bt<<<g1, 256, 0, stream>>>(Xn, wInB + (size_t)l * 2 * D_ * D_,
                                    b_in + l * 2 * D_, nullptr, uvb,
                                    Mrows, 2 * D_, D_);

    hipMemsetAsync(slots, 0, 64 * 64, stream);
    scan_kernel<<<8, 512, 0, stream>>>(uvb, wHB + (size_t)l * D_ * D_,
                                       b_h + l * D_, Hb, slots);

    dim3 g2(D_ / 128, Mrows / 128);
    gemm_hfrag<<<g2, 256, 0, stream>>>(Hb, wOutB + (size_t)l * D_ * D_,
                                       b_out + l * D_, lin, out,
                                       Mrows, D_, D_);
  }
}

// Round 5
// 17844.814 us; speedup vs baseline: 1.2792x; 1.2792x over previous
//
#include <hip/hip_runtime.h>
#include <stdint.h>
#include <stddef.h>

typedef __bf16 bf16;
typedef __bf16 bf16x8 __attribute__((ext_vector_type(8)));
typedef __bf16 bf16x4 __attribute__((ext_vector_type(4)));
typedef float  f32x4  __attribute__((ext_vector_type(4)));

#define B_ 8
#define T_ 2048
#define D_ 1024
#define L_ 2

#define AS1C(p) ((const __attribute__((address_space(1))) void*)(p))
#define AS3(p)  ((__attribute__((address_space(3))) void*)(p))

// Compact frame layout (h-state after step t), 16384 B per frame:
//   byte(t, b, n) = t*16384 + (n>>5)*512 + (((n&31)>>3)*8 + b)*16 + (n&7)*2
// b in [0,8), n in [0,1024). MFMA A-frags read it directly from LDS:
//   lane reads 16B at kk*512 + ((lane>>4)*8 + (lane&7))*16  (rows 8..15 of the
//   16-row fragment alias batches 0..7 -> finite dummies, discarded via C rows).
// uv layout (bf16): elem(t, n, b, p) = t*16384 + n*16 + b*2 + p   (p: 0=u,1=v)

// ---------------- f32 -> bf16 convert (weights) ----------------
__global__ __launch_bounds__(256) void cvt_kernel(const float* __restrict__ in,
                                                  bf16* __restrict__ out, int n4) {
  int i = blockIdx.x * 256 + threadIdx.x;
  if (i >= n4) return;
  float4 v = ((const float4*)in)[i];
  bf16x4 o = { (bf16)v.x, (bf16)v.y, (bf16)v.z, (bf16)v.w };
  ((bf16x4*)out)[i] = o;
}

// ---------------- LayerNorm ----------------
__global__ __launch_bounds__(256) void ln_kernel(const float* __restrict__ x,
                                                 const float* __restrict__ g,
                                                 const float* __restrict__ b,
                                                 bf16* __restrict__ xn) {
  const int row = blockIdx.x;
  const int tid = threadIdx.x;
  const float4 v = ((const float4*)(x + (size_t)row * D_))[tid];
  float s1 = v.x + v.y + v.z + v.w;
  float s2 = v.x * v.x + v.y * v.y + v.z * v.z + v.w * v.w;
#pragma unroll
  for (int off = 1; off < 64; off <<= 1) {
    s1 += __shfl_xor(s1, off);
    s2 += __shfl_xor(s2, off);
  }
  __shared__ float r1[4], r2[4];
  if ((tid & 63) == 0) { r1[tid >> 6] = s1; r2[tid >> 6] = s2; }
  __syncthreads();
  s1 = r1[0] + r1[1] + r1[2] + r1[3];
  s2 = r2[0] + r2[1] + r2[2] + r2[3];
  const float mu = s1 * (1.f / D_);
  const float var = s2 * (1.f / D_) - mu * mu;
  const float rs = rsqrtf(var + 1e-5f);
  const float4 gv = ((const float4*)g)[tid];
  const float4 bv = ((const float4*)b)[tid];
  bf16x4 o = { (bf16)((v.x - mu) * rs * gv.x + bv.x),
               (bf16)((v.y - mu) * rs * gv.y + bv.y),
               (bf16)((v.z - mu) * rs * gv.z + bv.z),
               (bf16)((v.w - mu) * rs * gv.w + bv.w) };
  ((bf16x4*)(xn + (size_t)row * D_))[tid] = o;
}

// ---- in_proj GEMM: C = Xn @ W_in^T + b_in, written as bf16 uv-interleaved ----
__global__ __launch_bounds__(256) void gemm_uv(const bf16* __restrict__ A,
                                               const bf16* __restrict__ Bw,
                                               const float* __restrict__ bias,
                                               bf16* __restrict__ uvp,
                                               int M, int N, int K) {
  __shared__ bf16 As[128 * 32];
  __shared__ bf16 Bs[128 * 32];
  const int tid = threadIdx.x;
  const int lane = tid & 63;
  const int wave = tid >> 6;
  const int m0 = blockIdx.y * 128;
  const int n0 = blockIdx.x * 128;
  const int wm = (wave >> 1) * 64;
  const int wn = (wave & 1) * 64;
  f32x4 acc[4][4] = {};

  for (int kt = 0; kt < K; kt += 32) {
#pragma unroll
    for (int it = 0; it < 2; ++it) {
      const int gidx = it * 256 + tid;
      const int row = gidx >> 2;
      const int col = (gidx & 3) << 3;
      __builtin_amdgcn_global_load_lds(AS1C(A + (size_t)(m0 + row) * K + kt + col),
                                       AS3(&As[gidx * 8]), 16, 0, 0);
      __builtin_amdgcn_global_load_lds(AS1C(Bw + (size_t)(n0 + row) * K + kt + col),
                                       AS3(&Bs[gidx * 8]), 16, 0, 0);
    }
    __syncthreads();
    bf16x8 af[4], bfr[4];
#pragma unroll
    for (int i = 0; i < 4; ++i)
      af[i] = *(const bf16x8*)&As[(wm + i * 16 + (lane & 15)) * 32 + (lane >> 4) * 8];
#pragma unroll
    for (int j = 0; j < 4; ++j)
      bfr[j] = *(const bf16x8*)&Bs[(wn + j * 16 + (lane & 15)) * 32 + (lane >> 4) * 8];
#pragma unroll
    for (int i = 0; i < 4; ++i)
#pragma unroll
      for (int j = 0; j < 4; ++j)
        acc[i][j] = __builtin_amdgcn_mfma_f32_16x16x32_bf16(af[i], bfr[j], acc[i][j], 0, 0, 0);
    __syncthreads();
  }

  const int cr = (lane >> 4) * 4;
  const int cc = lane & 15;
#pragma unroll
  for (int i = 0; i < 4; ++i) {
#pragma unroll
    for (int j = 0; j < 4; ++j) {
      const int mb = m0 + wm + i * 16 + cr;
      const int n = n0 + wn + j * 16 + cc;
      const float bn = bias[n];
      const int nn = n & 1023;
      const int p = n >> 10;
#pragma unroll
      for (int r = 0; r < 4; ++r) {
        const int row = mb + r;
        const int b = row >> 11;          // batch
        const int t = row & (T_ - 1);     // time
        uvp[(size_t)t * 16384 + nn * 16 + b * 2 + p] = (bf16)(acc[i][j][r] + bn);
      }
    }
  }
}

// ---- out_proj GEMM: A from compact frame-layout h buffer, +bias +resid ----
__global__ __launch_bounds__(256) void gemm_hfrag(const char* __restrict__ Hb,
                                                  const bf16* __restrict__ Bw,
                                                  const float* __restrict__ bias,
                                                  const float* __restrict__ resid,
                                                  float* __restrict__ C,
                                                  int M, int N, int K) {
  __shared__ bf16 As[128 * 32];
  __shared__ bf16 Bs[128 * 32];
  const int tid = threadIdx.x;
  const int lane = tid & 63;
  const int wave = tid >> 6;
  const int m0 = blockIdx.y * 128;
  const int n0 = blockIdx.x * 128;
  const int wm = (wave >> 1) * 64;
  const int wn = (wave & 1) * 64;
  f32x4 acc[4][4] = {};

  for (int kt = 0; kt < K; kt += 32) {
#pragma unroll
    for (int it = 0; it < 2; ++it) {
      const int g = it * 256 + tid;
      const int r = g >> 2;
      const int sub = g & 3;
      const int R = m0 + r;
      const int bb = R >> 11;
      const int tt = R & (T_ - 1);
      const char* src = Hb + (size_t)tt * 16384 + (size_t)(kt >> 5) * 512
                        + (sub * 8 + bb) * 16;
      __builtin_amdgcn_global_load_lds(AS1C(src), AS3(&As[g * 8]), 16, 0, 0);
      __builtin_amdgcn_global_load_lds(AS1C(Bw + (size_t)(n0 + r) * K + kt + (sub << 3)),
                                       AS3(&Bs[g * 8]), 16, 0, 0);
    }
    __syncthreads();
    bf16x8 af[4], bfr[4];
#pragma unroll
    for (int i = 0; i < 4; ++i)
      af[i] = *(const bf16x8*)&As[(wm + i * 16 + (lane & 15)) * 32 + (lane >> 4) * 8];
#pragma unroll
    for (int j = 0; j < 4; ++j)
      bfr[j] = *(const bf16x8*)&Bs[(wn + j * 16 + (lane & 15)) * 32 + (lane >> 4) * 8];
#pragma unroll
    for (int i = 0; i < 4; ++i)
#pragma unroll
      for (int j = 0; j < 4; ++j)
        acc[i][j] = __builtin_amdgcn_mfma_f32_16x16x32_bf16(af[i], bfr[j], acc[i][j], 0, 0, 0);
    __syncthreads();
  }

  const int cr = (lane >> 4) * 4;
  const int cc = lane & 15;
#pragma unroll
  for (int i = 0; i < 4; ++i) {
#pragma unroll
    for (int j = 0; j < 4; ++j) {
      const int mb = m0 + wm + i * 16 + cr;
      const int n = n0 + wn + j * 16 + cc;
      const float bn = bias[n];
#pragma unroll
      for (int r = 0; r < 4; ++r) {
        const size_t idx = (size_t)(mb + r) * N + n;
        C[idx] = acc[i][j][r] + bn + resid[idx];
      }
    }
  }
}

// ---------------- scan: 8 WGs x 512 thr, W_h pinned in VGPRs, MFMA recurrence --
// Sync: single global counter, release fetch_add per wave + lane-0 spin (r3).
// Publish: LDS transpose -> 32 contiguous 8B agent stores per wave (r4).
// Staging: compact 16KB frame -> LDS directly (2 loads/thread).
// uv: bf16 interleaved, one 16B load/lane, pipelined one step ahead.
__global__ __launch_bounds__(512, 2) void scan_kernel(const bf16* __restrict__ uvp,
                                                      const bf16* __restrict__ Wh,
                                                      const float* __restrict__ bh,
                                                      char* __restrict__ Hb,
                                                      unsigned* __restrict__ cnt) {
  const int tid = threadIdx.x;
  const int lane = tid & 63;
  const int wv = tid >> 6;
  const int Wg = blockIdx.x * 8 + wv;      // global wave id 0..63
  const int n0 = Wg * 16;                  // 16 output cols per wave
  const int kkw = Wg >> 1;                 // this wave's frame k-chunk
  const int c = lane & 15;                 // local col

  __shared__ __align__(16) char hC[2][16384];  // double-buffered compact frames
  __shared__ __align__(16) char tscr[8][256];  // per-wave publish transpose

  // W_h B-fragments: wB[kk] = W_h[n0+c][kk*32 + (lane>>4)*8 .. +8]
  bf16x8 wB[32];
#pragma unroll
  for (int kk = 0; kk < 32; ++kk)
    wB[kk] = *(const bf16x8*)(Wh + ((size_t)(n0 + c) << 10) + kk * 32 + ((lane >> 4) << 3));
#pragma unroll
  for (int kk = 0; kk < 32; ++kk)
    asm volatile("" : "+v"(wB[kk]));  // pin in VGPRs (defeat rematerialization)

  const float bh_n = bh[n0 + c];
  const int b0 = (lane >> 4) * 4;          // first batch (C-frag rows), lanes<32
  const int rdoff = ((lane >> 4) * 8 + (lane & 7)) * 16;  // A-frag read offset
  const int wregion = kkw * 512 + (Wg & 1) * 256;          // wave's 256B frame slice

  float hs0 = 0.f, hs1 = 0.f, hs2 = 0.f, hs3 = 0.f;

  // uv prefetch: lane reads (u,v) x 4 batches for col n0+c, one 16B load
  const bf16* uvbase = uvp + (size_t)(n0 + c) * 16 + b0 * 2;
  bf16x8 uvq = {};
  if (lane < 32) uvq = *(const bf16x8*)uvbase;  // t = 0

  for (int t = 0; t < T_; ++t) {
    f32x4 asum = {0.f, 0.f, 0.f, 0.f};
    if (t > 0) {
      // ---- wait: all 64 waves published frame[t-1] ----
      if (lane == 0) {
        const unsigned tgt = 64u * (unsigned)t;
        while (__hip_atomic_load(cnt, __ATOMIC_RELAXED, __HIP_MEMORY_SCOPE_AGENT) < tgt)
          __builtin_amdgcn_s_sleep(1);
        (void)__hip_atomic_load(cnt, __ATOMIC_ACQUIRE, __HIP_MEMORY_SCOPE_AGENT);
      }
      __builtin_amdgcn_sched_barrier(0);
      // ---- stage compact frame[t-1] (16KB) into LDS ----
      const char* srcF = Hb + (size_t)(t - 1) * 16384;
      char* dstF = hC[t & 1];
      __builtin_amdgcn_global_load_lds(AS1C(srcF + tid * 16), AS3(dstF + tid * 16), 16, 0, 0);
      __builtin_amdgcn_global_load_lds(AS1C(srcF + (512 + tid) * 16),
                                       AS3(dstF + (512 + tid) * 16), 16, 0, 0);
      __syncthreads();
      // ---- h @ W_h^T: 16 cols x 8 batches (frag rows 8..15 alias 0..7) ----
      f32x4 a0 = {0.f, 0.f, 0.f, 0.f}, a1 = {0.f, 0.f, 0.f, 0.f};
      f32x4 a2 = {0.f, 0.f, 0.f, 0.f}, a3 = {0.f, 0.f, 0.f, 0.f};
#pragma unroll
      for (int kk = 0; kk < 32; kk += 4) {
        bf16x8 f0 = *(const bf16x8*)(dstF + kk * 512 + rdoff);
        bf16x8 f1 = *(const bf16x8*)(dstF + (kk + 1) * 512 + rdoff);
        bf16x8 f2 = *(const bf16x8*)(dstF + (kk + 2) * 512 + rdoff);
        bf16x8 f3 = *(const bf16x8*)(dstF + (kk + 3) * 512 + rdoff);
        a0 = __builtin_amdgcn_mfma_f32_16x16x32_bf16(f0, wB[kk], a0, 0, 0, 0);
        a1 = __builtin_amdgcn_mfma_f32_16x16x32_bf16(f1, wB[kk + 1], a1, 0, 0, 0);
        a2 = __builtin_amdgcn_mfma_f32_16x16x32_bf16(f2, wB[kk + 2], a2, 0, 0, 0);
        a3 = __builtin_amdgcn_mfma_f32_16x16x32_bf16(f3, wB[kk + 3], a3, 0, 0, 0);
      }
      asum = (a0 + a1) + (a2 + a3);
      // no trailing barrier: hC double-buffered; protocol prevents 2-ahead reuse
    }

    // ---- epilogue: gate/cand, transpose via LDS, packed publish ----
    char* wscr = tscr[wv];
    if (lane < 32) {
#pragma unroll
      for (int r = 0; r < 4; ++r) {
        const float uu = (float)uvq[2 * r];
        const float vv = (float)uvq[2 * r + 1];
        float& hh = (r == 0) ? hs0 : (r == 1) ? hs1 : (r == 2) ? hs2 : hs3;
        const float s = asum[r] + bh_n + vv;
        const float g = __builtin_amdgcn_rcpf(1.f + __expf(-uu));
        const float e = __expf(2.f * s);
        const float cand = 1.f - 2.f * __builtin_amdgcn_rcpf(e + 1.f);
        hh = fmaf(g, cand - hh, hh);
        // scratch layout == frame slice layout: (c>>3)*128 + b*16 + (c&7)*2
        *(bf16*)(wscr + (c >> 3) * 128 + (b0 + r) * 16 + (c & 7) * 2) = (bf16)hh;
      }
    }
    asm volatile("s_waitcnt lgkmcnt(0)" ::: "memory");  // wave-local transpose done
    __builtin_amdgcn_sched_barrier(0);
    if (lane < 32) {
      const unsigned long long pv = *(const unsigned long long*)(wscr + lane * 8);
      char* dst = Hb + (size_t)t * 16384 + wregion + lane * 8;
      __hip_atomic_store((unsigned long long*)dst, pv,
                         __ATOMIC_RELAXED, __HIP_MEMORY_SCOPE_AGENT);
    }
    // ---- publish: release-add orders this wave's stores ----
    if (lane == 0)
      __hip_atomic_fetch_add(cnt, 1u, __ATOMIC_RELEASE, __HIP_MEMORY_SCOPE_AGENT);
    __builtin_amdgcn_sched_barrier(0);
    // ---- prefetch uv for t+1 (after release so it never delays it) ----
    if (lane < 32) uvq = *(const bf16x8*)(uvbase + (size_t)(t + 1) * 16384);
  }
}

extern "C" void kernel_launch(void* const* d_in, const int* in_sizes, int n_in,
                              void* d_out, int out_size, void* d_ws, size_t ws_size,
                              hipStream_t stream) {
  const float* x     = (const float*)d_in[0];
  const float* ln_g  = (const float*)d_in[1];
  const float* ln_b  = (const float*)d_in[2];
  const float* W_in  = (const float*)d_in[3];
  const float* b_in  = (const float*)d_in[4];
  const float* W_h   = (const float*)d_in[5];
  const float* b_h   = (const float*)d_in[6];
  const float* W_out = (const float*)d_in[7];
  const float* b_out = (const float*)d_in[8];
  float* out = (float*)d_out;

  char* ws = (char*)d_ws;
  size_t off = 0;
  auto alloc = [&](size_t bytes) -> void* {
    void* p = ws + off;
    off = (off + bytes + 255) & ~(size_t)255;
    return p;
  };
  bf16* wInB  = (bf16*)alloc((size_t)L_ * 2 * D_ * D_ * 2);
  bf16* wHB   = (bf16*)alloc((size_t)L_ * D_ * D_ * 2);
  bf16* wOutB = (bf16*)alloc((size_t)L_ * D_ * D_ * 2);
  bf16* Xn    = (bf16*)alloc((size_t)B_ * T_ * D_ * 2);
  bf16* uvp   = (bf16*)alloc(((size_t)T_ * 16384 + 16384) * 2);  // bf16 uv, +pad
  char* Hb    = (char*)alloc((size_t)T_ * 16384);   // compact h frames (32 MB)
  unsigned* cnt = (unsigned*)alloc(256);
  (void)ws_size; (void)in_sizes; (void)n_in; (void)out_size;  // ~143 MB used

  {
    int n4 = L_ * 2 * D_ * D_ / 4;
    cvt_kernel<<<(n4 + 255) / 256, 256, 0, stream>>>(W_in, wInB, n4);
    n4 = L_ * D_ * D_ / 4;
    cvt_kernel<<<(n4 + 255) / 256, 256, 0, stream>>>(W_h, wHB, n4);
    cvt_kernel<<<(n4 + 255) / 256, 256, 0, stream>>>(W_out, wOutB, n4);
  }

  const int Mrows = B_ * T_;  // 16384
  for (int l = 0; l < L_; ++l) {
    const float* lin = (l == 0) ? x : out;
    ln_kernel<<<Mrows, 256, 0, stream>>>(lin, ln_g + l * D_, ln_b + l * D_, Xn);

    dim3 g1(2 * D_ / 128, Mrows / 128);
    gemm_uv<<<g1, 256, 0, stream>>>(Xn, wInB + (size_t)l * 2 * D_ * D_,
                                    b_in + l * 2 * D_, uvp,
                                    Mrows, 2 * D_, D_);

    hipMemsetAsync(cnt, 0, 4, stream);
    scan_kernel<<<8, 512, 0, stream>>>(uvp, wHB + (size_t)l * D_ * D_,
                                       b_h + l * D_, Hb, cnt);

    dim3 g2(D_ / 128, Mrows / 128);
    gemm_hfrag<<<g2, 256, 0, stream>>>(Hb, wOutB + (size_t)l * D_ * D_,
                                       b_out + l * D_, lin, out,
                                       Mrows, D_, D_);
  }
}

// Round 6
// 15065.591 us; speedup vs baseline: 1.5152x; 1.1845x over previous
//
#include <hip/hip_runtime.h>
#include <stdint.h>
#include <stddef.h>

typedef __bf16 bf16;
typedef __bf16 bf16x8 __attribute__((ext_vector_type(8)));
typedef __bf16 bf16x4 __attribute__((ext_vector_type(4)));
typedef float  f32x4  __attribute__((ext_vector_type(4)));

#define B_ 8
#define T_ 2048
#define D_ 1024
#define L_ 2

#define AS1C(p) ((const __attribute__((address_space(1))) void*)(p))
#define AS3(p)  ((__attribute__((address_space(3))) void*)(p))

// Compact frame layout (h-state after step t), 16384 B per frame:
//   byte(t, b, n) = t*16384 + (n>>5)*512 + (((n&31)>>3)*8 + b)*16 + (n&7)*2
// uv layout (bf16): elem(t, n, b, p) = t*16384 + n*16 + b*2 + p   (p: 0=u,1=v)

// ---------------- f32 -> bf16 convert (weights) ----------------
__global__ __launch_bounds__(256) void cvt_kernel(const float* __restrict__ in,
                                                  bf16* __restrict__ out, int n4) {
  int i = blockIdx.x * 256 + threadIdx.x;
  if (i >= n4) return;
  float4 v = ((const float4*)in)[i];
  bf16x4 o = { (bf16)v.x, (bf16)v.y, (bf16)v.z, (bf16)v.w };
  ((bf16x4*)out)[i] = o;
}

// ---------------- LayerNorm ----------------
__global__ __launch_bounds__(256) void ln_kernel(const float* __restrict__ x,
                                                 const float* __restrict__ g,
                                                 const float* __restrict__ b,
                                                 bf16* __restrict__ xn) {
  const int row = blockIdx.x;
  const int tid = threadIdx.x;
  const float4 v = ((const float4*)(x + (size_t)row * D_))[tid];
  float s1 = v.x + v.y + v.z + v.w;
  float s2 = v.x * v.x + v.y * v.y + v.z * v.z + v.w * v.w;
#pragma unroll
  for (int off = 1; off < 64; off <<= 1) {
    s1 += __shfl_xor(s1, off);
    s2 += __shfl_xor(s2, off);
  }
  __shared__ float r1[4], r2[4];
  if ((tid & 63) == 0) { r1[tid >> 6] = s1; r2[tid >> 6] = s2; }
  __syncthreads();
  s1 = r1[0] + r1[1] + r1[2] + r1[3];
  s2 = r2[0] + r2[1] + r2[2] + r2[3];
  const float mu = s1 * (1.f / D_);
  const float var = s2 * (1.f / D_) - mu * mu;
  const float rs = rsqrtf(var + 1e-5f);
  const float4 gv = ((const float4*)g)[tid];
  const float4 bv = ((const float4*)b)[tid];
  bf16x4 o = { (bf16)((v.x - mu) * rs * gv.x + bv.x),
               (bf16)((v.y - mu) * rs * gv.y + bv.y),
               (bf16)((v.z - mu) * rs * gv.z + bv.z),
               (bf16)((v.w - mu) * rs * gv.w + bv.w) };
  ((bf16x4*)(xn + (size_t)row * D_))[tid] = o;
}

// ---- in_proj GEMM: C = Xn @ W_in^T + b_in, written as bf16 uv-interleaved ----
__global__ __launch_bounds__(256) void gemm_uv(const bf16* __restrict__ A,
                                               const bf16* __restrict__ Bw,
                                               const float* __restrict__ bias,
                                               bf16* __restrict__ uvp,
                                               int M, int N, int K) {
  __shared__ bf16 As[128 * 32];
  __shared__ bf16 Bs[128 * 32];
  const int tid = threadIdx.x;
  const int lane = tid & 63;
  const int wave = tid >> 6;
  const int m0 = blockIdx.y * 128;
  const int n0 = blockIdx.x * 128;
  const int wm = (wave >> 1) * 64;
  const int wn = (wave & 1) * 64;
  f32x4 acc[4][4] = {};

  for (int kt = 0; kt < K; kt += 32) {
#pragma unroll
    for (int it = 0; it < 2; ++it) {
      const int gidx = it * 256 + tid;
      const int row = gidx >> 2;
      const int col = (gidx & 3) << 3;
      __builtin_amdgcn_global_load_lds(AS1C(A + (size_t)(m0 + row) * K + kt + col),
                                       AS3(&As[gidx * 8]), 16, 0, 0);
      __builtin_amdgcn_global_load_lds(AS1C(Bw + (size_t)(n0 + row) * K + kt + col),
                                       AS3(&Bs[gidx * 8]), 16, 0, 0);
    }
    __syncthreads();
    bf16x8 af[4], bfr[4];
#pragma unroll
    for (int i = 0; i < 4; ++i)
      af[i] = *(const bf16x8*)&As[(wm + i * 16 + (lane & 15)) * 32 + (lane >> 4) * 8];
#pragma unroll
    for (int j = 0; j < 4; ++j)
      bfr[j] = *(const bf16x8*)&Bs[(wn + j * 16 + (lane & 15)) * 32 + (lane >> 4) * 8];
#pragma unroll
    for (int i = 0; i < 4; ++i)
#pragma unroll
      for (int j = 0; j < 4; ++j)
        acc[i][j] = __builtin_amdgcn_mfma_f32_16x16x32_bf16(af[i], bfr[j], acc[i][j], 0, 0, 0);
    __syncthreads();
  }

  const int cr = (lane >> 4) * 4;
  const int cc = lane & 15;
#pragma unroll
  for (int i = 0; i < 4; ++i) {
#pragma unroll
    for (int j = 0; j < 4; ++j) {
      const int mb = m0 + wm + i * 16 + cr;
      const int n = n0 + wn + j * 16 + cc;
      const float bn = bias[n];
      const int nn = n & 1023;
      const int p = n >> 10;
#pragma unroll
      for (int r = 0; r < 4; ++r) {
        const int row = mb + r;
        const int b = row >> 11;          // batch
        const int t = row & (T_ - 1);     // time
        uvp[(size_t)t * 16384 + nn * 16 + b * 2 + p] = (bf16)(acc[i][j][r] + bn);
      }
    }
  }
}

// ---- out_proj GEMM: A from compact frame-layout h buffer, +bias +resid ----
__global__ __launch_bounds__(256) void gemm_hfrag(const char* __restrict__ Hb,
                                                  const bf16* __restrict__ Bw,
                                                  const float* __restrict__ bias,
                                                  const float* __restrict__ resid,
                                                  float* __restrict__ C,
                                                  int M, int N, int K) {
  __shared__ bf16 As[128 * 32];
  __shared__ bf16 Bs[128 * 32];
  const int tid = threadIdx.x;
  const int lane = tid & 63;
  const int wave = tid >> 6;
  const int m0 = blockIdx.y * 128;
  const int n0 = blockIdx.x * 128;
  const int wm = (wave >> 1) * 64;
  const int wn = (wave & 1) * 64;
  f32x4 acc[4][4] = {};

  for (int kt = 0; kt < K; kt += 32) {
#pragma unroll
    for (int it = 0; it < 2; ++it) {
      const int g = it * 256 + tid;
      const int r = g >> 2;
      const int sub = g & 3;
      const int R = m0 + r;
      const int bb = R >> 11;
      const int tt = R & (T_ - 1);
      const char* src = Hb + (size_t)tt * 16384 + (size_t)(kt >> 5) * 512
                        + (sub * 8 + bb) * 16;
      __builtin_amdgcn_global_load_lds(AS1C(src), AS3(&As[g * 8]), 16, 0, 0);
      __builtin_amdgcn_global_load_lds(AS1C(Bw + (size_t)(n0 + r) * K + kt + (sub << 3)),
                                       AS3(&Bs[g * 8]), 16, 0, 0);
    }
    __syncthreads();
    bf16x8 af[4], bfr[4];
#pragma unroll
    for (int i = 0; i < 4; ++i)
      af[i] = *(const bf16x8*)&As[(wm + i * 16 + (lane & 15)) * 32 + (lane >> 4) * 8];
#pragma unroll
    for (int j = 0; j < 4; ++j)
      bfr[j] = *(const bf16x8*)&Bs[(wn + j * 16 + (lane & 15)) * 32 + (lane >> 4) * 8];
#pragma unroll
    for (int i = 0; i < 4; ++i)
#pragma unroll
      for (int j = 0; j < 4; ++j)
        acc[i][j] = __builtin_amdgcn_mfma_f32_16x16x32_bf16(af[i], bfr[j], acc[i][j], 0, 0, 0);
    __syncthreads();
  }

  const int cr = (lane >> 4) * 4;
  const int cc = lane & 15;
#pragma unroll
  for (int i = 0; i < 4; ++i) {
#pragma unroll
    for (int j = 0; j < 4; ++j) {
      const int mb = m0 + wm + i * 16 + cr;
      const int n = n0 + wn + j * 16 + cc;
      const float bn = bias[n];
#pragma unroll
      for (int r = 0; r < 4; ++r) {
        const size_t idx = (size_t)(mb + r) * N + n;
        C[idx] = acc[i][j][r] + bn + resid[idx];
      }
    }
  }
}

// ---------------- scan: 8 WGs x 512 thr, W_h resident in VGPRs (256-cap) ------
// Sync: per-WG slot release-store (no RMW); each wave polls 8 slots (lanes 0-7).
// Publish: LDS transpose -> 32 contiguous 8B agent stores; __syncthreads drains
// all waves' stores before the WG's slot store.
__global__ __launch_bounds__(512, 1) void scan_kernel(const bf16* __restrict__ uvp,
                                                      const bf16* __restrict__ Wh,
                                                      const float* __restrict__ bh,
                                                      char* __restrict__ Hb,
                                                      unsigned* __restrict__ slots) {
  const int tid = threadIdx.x;
  const int lane = tid & 63;
  const int wv = tid >> 6;
  const int Wg = blockIdx.x * 8 + wv;      // global wave id 0..63
  const int n0 = Wg * 16;                  // 16 output cols per wave
  const int kkw = Wg >> 1;                 // this wave's frame k-chunk
  const int c = lane & 15;                 // local col

  __shared__ __align__(16) char hC[2][16384];  // double-buffered compact frames
  __shared__ __align__(16) char tscr[8][256];  // per-wave publish transpose

  // W_h B-fragments: wB[kk] = W_h[n0+c][kk*32 + (lane>>4)*8 .. +8]
  bf16x8 wB[32];
#pragma unroll
  for (int kk = 0; kk < 32; ++kk)
    wB[kk] = *(const bf16x8*)(Wh + ((size_t)(n0 + c) << 10) + kk * 32 + ((lane >> 4) << 3));
#pragma unroll
  for (int kk = 0; kk < 32; ++kk)
    asm volatile("" : "+v"(wB[kk]));  // keep resident (256-VGPR budget now)

  const float bh_n = bh[n0 + c];
  const int b0 = (lane >> 4) * 4;          // first batch (C-frag rows), lanes<32
  const int rdoff = ((lane >> 4) * 8 + (lane & 7)) * 16;  // A-frag read offset
  const int wregion = kkw * 512 + (Wg & 1) * 256;          // wave's 256B frame slice

  float hs0 = 0.f, hs1 = 0.f, hs2 = 0.f, hs3 = 0.f;

  // uv prefetch: lane reads (u,v) x 4 batches for col n0+c, one 16B load
  const bf16* uvbase = uvp + (size_t)(n0 + c) * 16 + b0 * 2;
  bf16x8 uvq = {};
  if (lane < 32) uvq = *(const bf16x8*)uvbase;  // t = 0

  for (int t = 0; t < T_; ++t) {
    f32x4 asum = {0.f, 0.f, 0.f, 0.f};
    if (t > 0) {
      // ---- wait: all 8 WGs published frame[t-1] (8-slot parallel poll) ----
      const unsigned tgt = (unsigned)t;
      unsigned sv = (lane < 8)
        ? __hip_atomic_load(slots + lane * 16, __ATOMIC_RELAXED, __HIP_MEMORY_SCOPE_AGENT)
        : tgt;
      while (!__all((int)(sv >= tgt))) {
        __builtin_amdgcn_s_sleep(1);
        if (lane < 8)
          sv = __hip_atomic_load(slots + lane * 16, __ATOMIC_RELAXED, __HIP_MEMORY_SCOPE_AGENT);
      }
      (void)__hip_atomic_load(slots, __ATOMIC_ACQUIRE, __HIP_MEMORY_SCOPE_AGENT);
      __builtin_amdgcn_sched_barrier(0);
      // ---- stage compact frame[t-1] (16KB) into LDS ----
      const char* srcF = Hb + (size_t)(t - 1) * 16384;
      char* dstF = hC[t & 1];
      __builtin_amdgcn_global_load_lds(AS1C(srcF + tid * 16), AS3(dstF + tid * 16), 16, 0, 0);
      __builtin_amdgcn_global_load_lds(AS1C(srcF + (512 + tid) * 16),
                                       AS3(dstF + (512 + tid) * 16), 16, 0, 0);
      __syncthreads();
      // ---- h @ W_h^T: 16 cols x 8 batches (frag rows 8..15 alias 0..7) ----
      f32x4 a0 = {0.f, 0.f, 0.f, 0.f}, a1 = {0.f, 0.f, 0.f, 0.f};
      f32x4 a2 = {0.f, 0.f, 0.f, 0.f}, a3 = {0.f, 0.f, 0.f, 0.f};
#pragma unroll
      for (int kk = 0; kk < 32; kk += 4) {
        bf16x8 f0 = *(const bf16x8*)(dstF + kk * 512 + rdoff);
        bf16x8 f1 = *(const bf16x8*)(dstF + (kk + 1) * 512 + rdoff);
        bf16x8 f2 = *(const bf16x8*)(dstF + (kk + 2) * 512 + rdoff);
        bf16x8 f3 = *(const bf16x8*)(dstF + (kk + 3) * 512 + rdoff);
        a0 = __builtin_amdgcn_mfma_f32_16x16x32_bf16(f0, wB[kk], a0, 0, 0, 0);
        a1 = __builtin_amdgcn_mfma_f32_16x16x32_bf16(f1, wB[kk + 1], a1, 0, 0, 0);
        a2 = __builtin_amdgcn_mfma_f32_16x16x32_bf16(f2, wB[kk + 2], a2, 0, 0, 0);
        a3 = __builtin_amdgcn_mfma_f32_16x16x32_bf16(f3, wB[kk + 3], a3, 0, 0, 0);
      }
      asum = (a0 + a1) + (a2 + a3);
    }

    // ---- epilogue: gate/cand, transpose via LDS, packed publish ----
    char* wscr = tscr[wv];
    if (lane < 32) {
#pragma unroll
      for (int r = 0; r < 4; ++r) {
        const float uu = (float)uvq[2 * r];
        const float vv = (float)uvq[2 * r + 1];
        float& hh = (r == 0) ? hs0 : (r == 1) ? hs1 : (r == 2) ? hs2 : hs3;
        const float s = asum[r] + bh_n + vv;
        const float g = __builtin_amdgcn_rcpf(1.f + __expf(-uu));
        const float e = __expf(2.f * s);
        const float cand = 1.f - 2.f * __builtin_amdgcn_rcpf(e + 1.f);
        hh = fmaf(g, cand - hh, hh);
        // scratch layout == frame slice layout: (c>>3)*128 + b*16 + (c&7)*2
        *(bf16*)(wscr + (c >> 3) * 128 + (b0 + r) * 16 + (c & 7) * 2) = (bf16)hh;
      }
    }
    asm volatile("s_waitcnt lgkmcnt(0)" ::: "memory");  // wave-local transpose done
    __builtin_amdgcn_sched_barrier(0);
    if (lane < 32) {
      const unsigned long long pv = *(const unsigned long long*)(wscr + lane * 8);
      char* dst = Hb + (size_t)t * 16384 + wregion + lane * 8;
      __hip_atomic_store((unsigned long long*)dst, pv,
                         __ATOMIC_RELAXED, __HIP_MEMORY_SCOPE_AGENT);
    }
    // ---- drain ALL waves' publish stores, then one release slot-store per WG --
    __syncthreads();
    if (tid == 0)
      __hip_atomic_store(slots + blockIdx.x * 16, (unsigned)(t + 1),
                         __ATOMIC_RELEASE, __HIP_MEMORY_SCOPE_AGENT);
    __builtin_amdgcn_sched_barrier(0);
    // ---- prefetch uv for t+1 (after slot store so it never delays it) ----
    if (lane < 32) uvq = *(const bf16x8*)(uvbase + (size_t)(t + 1) * 16384);
  }
}

extern "C" void kernel_launch(void* const* d_in, const int* in_sizes, int n_in,
                              void* d_out, int out_size, void* d_ws, size_t ws_size,
                              hipStream_t stream) {
  const float* x     = (const float*)d_in[0];
  const float* ln_g  = (const float*)d_in[1];
  const float* ln_b  = (const float*)d_in[2];
  const float* W_in  = (const float*)d_in[3];
  const float* b_in  = (const float*)d_in[4];
  const float* W_h   = (const float*)d_in[5];
  const float* b_h   = (const float*)d_in[6];
  const float* W_out = (const float*)d_in[7];
  const float* b_out = (const float*)d_in[8];
  float* out = (float*)d_out;

  char* ws = (char*)d_ws;
  size_t off = 0;
  auto alloc = [&](size_t bytes) -> void* {
    void* p = ws + off;
    off = (off + bytes + 255) & ~(size_t)255;
    return p;
  };
  bf16* wInB  = (bf16*)alloc((size_t)L_ * 2 * D_ * D_ * 2);
  bf16* wHB   = (bf16*)alloc((size_t)L_ * D_ * D_ * 2);
  bf16* wOutB = (bf16*)alloc((size_t)L_ * D_ * D_ * 2);
  bf16* Xn    = (bf16*)alloc((size_t)B_ * T_ * D_ * 2);
  bf16* uvp   = (bf16*)alloc(((size_t)T_ * 16384 + 16384) * 2);  // bf16 uv, +pad
  char* Hb    = (char*)alloc((size_t)T_ * 16384);   // compact h frames (32 MB)
  unsigned* slots = (unsigned*)alloc(512);          // 8 per-WG slots, 64B apart
  (void)ws_size; (void)in_sizes; (void)n_in; (void)out_size;  // ~143 MB used

  {
    int n4 = L_ * 2 * D_ * D_ / 4;
    cvt_kernel<<<(n4 + 255) / 256, 256, 0, stream>>>(W_in, wInB, n4);
    n4 = L_ * D_ * D_ / 4;
    cvt_kernel<<<(n4 + 255) / 256, 256, 0, stream>>>(W_h, wHB, n4);
    cvt_kernel<<<(n4 + 255) / 256, 256, 0, stream>>>(W_out, wOutB, n4);
  }

  const int Mrows = B_ * T_;  // 16384
  for (int l = 0; l < L_; ++l) {
    const float* lin = (l == 0) ? x : out;
    ln_kernel<<<Mrows, 256, 0, stream>>>(lin, ln_g + l * D_, ln_b + l * D_, Xn);

    dim3 g1(2 * D_ / 128, Mrows / 128);
    gemm_uv<<<g1, 256, 0, stream>>>(Xn, wInB + (size_t)l * 2 * D_ * D_,
                                    b_in + l * 2 * D_, uvp,
                                    Mrows, 2 * D_, D_);

    hipMemsetAsync(slots, 0, 512, stream);
    scan_kernel<<<8, 512, 0, stream>>>(uvp, wHB + (size_t)l * D_ * D_,
                                       b_h + l * D_, Hb, slots);

    dim3 g2(D_ / 128, Mrows / 128);
    gemm_hfrag<<<g2, 256, 0, stream>>>(Hb, wOutB + (size_t)l * D_ * D_,
                                       b_out + l * D_, lin, out,
                                       Mrows, D_, D_);
  }
}